// Round 1
// baseline (19476.010 us; speedup 1.0000x reference)
//
#include <hip/hip_runtime.h>
#include <math.h>

#define BATCH 4096
#define IDIM 1024
#define LDIM 1024
#define HDIM 2048
#define ODIM 512
#define GDIM 3072   // 3*LDIM
#define JDIM 1536   // IDIM+ODIM == LDIM+ODIM
#define INNER 4
#define OUTER 8

__device__ __forceinline__ float sigmoidf_(float x) {
  return 1.0f / (1.0f + expf(-x));
}

// dst[B,1536] = [a (B,1024) | b (B,512)], float4 granularity
__global__ void concat_kernel(float* __restrict__ dst,
                              const float* __restrict__ a,
                              const float* __restrict__ b) {
  int idx = blockIdx.x * 256 + threadIdx.x;
  const int total = BATCH * (JDIM / 4);
  if (idx >= total) return;
  int row = idx / (JDIM / 4);
  int c4 = idx - row * (JDIM / 4);
  float4 v;
  if (c4 < IDIM / 4)
    v = ((const float4*)a)[row * (IDIM / 4) + c4];
  else
    v = ((const float4*)b)[row * (ODIM / 4) + (c4 - IDIM / 4)];
  ((float4*)dst)[idx] = v;
}

// C[M,N] = act(A[M,K] @ W[N,K]^T + bias[N])
// ACT: 0 = none, 1 = relu, 2 = write pre-act to C and tanh(pre-act) to C2
// M=BATCH fixed. 64x64 tile, 256 threads, 4x4 per thread, K%16==0.
template <int ACT>
__global__ __launch_bounds__(256) void sgemm_kernel(
    const float* __restrict__ A, const float* __restrict__ W,
    const float* __restrict__ bias, float* __restrict__ C,
    float* __restrict__ C2, int N, int K) {
  __shared__ float sA[16][68];
  __shared__ float sW[16][68];
  const int tid = threadIdx.x;
  const int tx = tid & 15;
  const int ty = tid >> 4;
  const int m0 = blockIdx.y * 64;
  const int n0 = blockIdx.x * 64;
  const int lrow = tid >> 2;          // 0..63
  const int lcol = (tid & 3) << 2;    // 0,4,8,12
  const float* Ap = A + (size_t)(m0 + lrow) * K + lcol;
  const float* Wp = W + (size_t)(n0 + lrow) * K + lcol;
  float acc[4][4] = {};
  for (int k0 = 0; k0 < K; k0 += 16) {
    float4 av = *(const float4*)(Ap + k0);
    float4 wv = *(const float4*)(Wp + k0);
    __syncthreads();
    sA[lcol + 0][lrow] = av.x; sA[lcol + 1][lrow] = av.y;
    sA[lcol + 2][lrow] = av.z; sA[lcol + 3][lrow] = av.w;
    sW[lcol + 0][lrow] = wv.x; sW[lcol + 1][lrow] = wv.y;
    sW[lcol + 2][lrow] = wv.z; sW[lcol + 3][lrow] = wv.w;
    __syncthreads();
#pragma unroll
    for (int kk = 0; kk < 16; ++kk) {
      float4 a4 = *(const float4*)&sA[kk][ty * 4];
      float4 w4 = *(const float4*)&sW[kk][tx * 4];
      float a[4] = {a4.x, a4.y, a4.z, a4.w};
      float w[4] = {w4.x, w4.y, w4.z, w4.w};
#pragma unroll
      for (int i = 0; i < 4; ++i)
#pragma unroll
        for (int j = 0; j < 4; ++j) acc[i][j] = fmaf(a[i], w[j], acc[i][j]);
    }
  }
  float4 bb = *(const float4*)&bias[n0 + tx * 4];
  float bv[4] = {bb.x, bb.y, bb.z, bb.w};
#pragma unroll
  for (int i = 0; i < 4; ++i) {
    int m = m0 + ty * 4 + i;
    float o[4];
#pragma unroll
    for (int j = 0; j < 4; ++j) {
      float v = acc[i][j] + bv[j];
      if (ACT == 1) v = fmaxf(v, 0.0f);
      o[j] = v;
    }
    float4 ov = {o[0], o[1], o[2], o[3]};
    *(float4*)&C[(size_t)m * N + n0 + tx * 4] = ov;
    if (ACT == 2) {
      float4 tv = {tanhf(o[0]), tanhf(o[1]), tanhf(o[2]), tanhf(o[3])};
      *(float4*)&C2[(size_t)m * N + n0 + tx * 4] = tv;
    }
  }
}

// Fused GRU cycle: computes h_gates = state @ W_hh^T + b_hh for all 3 gates
// (3 accumulator sets) and applies the full gate update in the epilogue.
// state_out[b,l] = (1-z)*n + z*state[b,l]
__global__ __launch_bounds__(256) void gru_kernel(
    const float* __restrict__ state, const float* __restrict__ Whh,
    const float* __restrict__ bhh, const float* __restrict__ xg,
    float* __restrict__ state_out) {
  __shared__ float sA[16][68];
  __shared__ float sR[16][68];
  __shared__ float sZ[16][68];
  __shared__ float sN[16][68];
  const int tid = threadIdx.x;
  const int tx = tid & 15;
  const int ty = tid >> 4;
  const int m0 = blockIdx.y * 64;
  const int n0 = blockIdx.x * 64;
  const int lrow = tid >> 2;
  const int lcol = (tid & 3) << 2;
  const float* Ap = state + (size_t)(m0 + lrow) * LDIM + lcol;
  const float* Rp = Whh + (size_t)(n0 + lrow) * LDIM + lcol;
  const float* Zp = Rp + (size_t)LDIM * LDIM;
  const float* Np = Zp + (size_t)LDIM * LDIM;
  float accr[4][4] = {}, accz[4][4] = {}, accn[4][4] = {};
  for (int k0 = 0; k0 < LDIM; k0 += 16) {
    float4 av = *(const float4*)(Ap + k0);
    float4 rv = *(const float4*)(Rp + k0);
    float4 zv = *(const float4*)(Zp + k0);
    float4 nv = *(const float4*)(Np + k0);
    __syncthreads();
    sA[lcol + 0][lrow] = av.x; sA[lcol + 1][lrow] = av.y;
    sA[lcol + 2][lrow] = av.z; sA[lcol + 3][lrow] = av.w;
    sR[lcol + 0][lrow] = rv.x; sR[lcol + 1][lrow] = rv.y;
    sR[lcol + 2][lrow] = rv.z; sR[lcol + 3][lrow] = rv.w;
    sZ[lcol + 0][lrow] = zv.x; sZ[lcol + 1][lrow] = zv.y;
    sZ[lcol + 2][lrow] = zv.z; sZ[lcol + 3][lrow] = zv.w;
    sN[lcol + 0][lrow] = nv.x; sN[lcol + 1][lrow] = nv.y;
    sN[lcol + 2][lrow] = nv.z; sN[lcol + 3][lrow] = nv.w;
    __syncthreads();
#pragma unroll
    for (int kk = 0; kk < 16; ++kk) {
      float4 a4 = *(const float4*)&sA[kk][ty * 4];
      float4 r4 = *(const float4*)&sR[kk][tx * 4];
      float4 z4 = *(const float4*)&sZ[kk][tx * 4];
      float4 n4 = *(const float4*)&sN[kk][tx * 4];
      float a[4] = {a4.x, a4.y, a4.z, a4.w};
      float r[4] = {r4.x, r4.y, r4.z, r4.w};
      float z[4] = {z4.x, z4.y, z4.z, z4.w};
      float n[4] = {n4.x, n4.y, n4.z, n4.w};
#pragma unroll
      for (int i = 0; i < 4; ++i)
#pragma unroll
        for (int j = 0; j < 4; ++j) {
          accr[i][j] = fmaf(a[i], r[j], accr[i][j]);
          accz[i][j] = fmaf(a[i], z[j], accz[i][j]);
          accn[i][j] = fmaf(a[i], n[j], accn[i][j]);
        }
    }
  }
  float4 br4 = *(const float4*)&bhh[n0 + tx * 4];
  float4 bz4 = *(const float4*)&bhh[LDIM + n0 + tx * 4];
  float4 bn4 = *(const float4*)&bhh[2 * LDIM + n0 + tx * 4];
  float br[4] = {br4.x, br4.y, br4.z, br4.w};
  float bz[4] = {bz4.x, bz4.y, bz4.z, bz4.w};
  float bn[4] = {bn4.x, bn4.y, bn4.z, bn4.w};
#pragma unroll
  for (int i = 0; i < 4; ++i) {
    int m = m0 + ty * 4 + i;
    const float* xgp = xg + (size_t)m * GDIM + n0 + tx * 4;
    float4 xr4 = *(const float4*)(xgp);
    float4 xz4 = *(const float4*)(xgp + LDIM);
    float4 xn4 = *(const float4*)(xgp + 2 * LDIM);
    float4 sv4 = *(const float4*)&state[(size_t)m * LDIM + n0 + tx * 4];
    float xr[4] = {xr4.x, xr4.y, xr4.z, xr4.w};
    float xz[4] = {xz4.x, xz4.y, xz4.z, xz4.w};
    float xn[4] = {xn4.x, xn4.y, xn4.z, xn4.w};
    float sv[4] = {sv4.x, sv4.y, sv4.z, sv4.w};
    float o[4];
#pragma unroll
    for (int j = 0; j < 4; ++j) {
      float r = sigmoidf_(xr[j] + accr[i][j] + br[j]);
      float z = sigmoidf_(xz[j] + accz[i][j] + bz[j]);
      float n = tanhf(xn[j] + r * (accn[i][j] + bn[j]));
      o[j] = (1.0f - z) * n + z * sv[j];
    }
    float4 ov = {o[0], o[1], o[2], o[3]};
    *(float4*)&state_out[(size_t)m * LDIM + n0 + tx * 4] = ov;
  }
}

// halt = h2[B,1024] @ hw2[2,1024]^T + hb2[2]; one wave per row.
__global__ __launch_bounds__(256) void halt_kernel(
    const float* __restrict__ h2, const float* __restrict__ hw2,
    const float* __restrict__ hb2, float* __restrict__ out) {
  int wave = (blockIdx.x * 256 + threadIdx.x) >> 6;
  int lane = threadIdx.x & 63;
  if (wave >= BATCH) return;
  const float* row = h2 + (size_t)wave * LDIM;
  float s0 = 0.0f, s1 = 0.0f;
#pragma unroll
  for (int k = lane; k < LDIM; k += 64) {
    float v = row[k];
    s0 = fmaf(v, hw2[k], s0);
    s1 = fmaf(v, hw2[LDIM + k], s1);
  }
#pragma unroll
  for (int off = 32; off > 0; off >>= 1) {
    s0 += __shfl_xor(s0, off);
    s1 += __shfl_xor(s1, off);
  }
  if (lane == 0) {
    out[(size_t)wave * 2 + 0] = s0 + hb2[0];
    out[(size_t)wave * 2 + 1] = s1 + hb2[1];
  }
}

extern "C" void kernel_launch(void* const* d_in, const int* in_sizes, int n_in,
                              void* d_out, int out_size, void* d_ws, size_t ws_size,
                              hipStream_t stream) {
  const float* inputs = (const float*)d_in[0];
  const float* W_ih = (const float*)d_in[1];
  const float* W_hh = (const float*)d_in[2];
  const float* b_ih = (const float*)d_in[3];
  const float* b_hh = (const float*)d_in[4];
  const float* aw1 = (const float*)d_in[5];
  const float* ab1 = (const float*)d_in[6];
  const float* aw2 = (const float*)d_in[7];
  const float* ab2 = (const float*)d_in[8];
  const float* hw1 = (const float*)d_in[9];
  const float* hb1 = (const float*)d_in[10];
  const float* hw2 = (const float*)d_in[11];
  const float* hb2 = (const float*)d_in[12];
  // d_in[13]=inner_cycles(4), d_in[14]=outer_steps(8) — fixed by setup_inputs.

  float* out = (float*)d_out;
  float* logits_out = out;                                  // [8, B, 512]
  float* halt_out = out + (size_t)OUTER * BATCH * ODIM;     // [8, B, 2]

  float* ws = (float*)d_ws;
  float* state_a = ws;                        // B*1024
  float* state_b = state_a + (size_t)BATCH * LDIM;
  float* ans = state_b + (size_t)BATCH * LDIM;          // B*512
  float* cat = ans + (size_t)BATCH * ODIM;              // B*1536
  float* xg = cat + (size_t)BATCH * JDIM;               // B*3072
  float* h1 = xg;                                       // reuse (B*2048)
  float* h2 = xg + (size_t)BATCH * HDIM;                // reuse (B*1024)

  hipMemsetAsync(state_a, 0, (size_t)BATCH * LDIM * sizeof(float), stream);
  hipMemsetAsync(ans, 0, (size_t)BATCH * ODIM * sizeof(float), stream);

  const int concat_blocks = (BATCH * (JDIM / 4) + 255) / 256;
  for (int s = 0; s < OUTER; ++s) {
    // x = [inputs | ans];  x_gates = x @ W_ih^T + b_ih
    concat_kernel<<<concat_blocks, 256, 0, stream>>>(cat, inputs, ans);
    sgemm_kernel<0><<<dim3(GDIM / 64, BATCH / 64), 256, 0, stream>>>(
        cat, W_ih, b_ih, xg, nullptr, GDIM, JDIM);
    // 4 fused GRU cycles, ping-pong state (even count -> ends in state_a)
    float* cur = state_a;
    float* nxt = state_b;
    for (int c = 0; c < INNER; ++c) {
      gru_kernel<<<dim3(LDIM / 64, BATCH / 64), 256, 0, stream>>>(
          cur, W_hh, b_hh, xg, nxt);
      float* t = cur; cur = nxt; nxt = t;
    }
    // joint = [state | ans]
    concat_kernel<<<concat_blocks, 256, 0, stream>>>(cat, state_a, ans);
    // h1 = relu(joint @ aw1^T + ab1)   (overwrites xg region — xg is dead now)
    sgemm_kernel<1><<<dim3(HDIM / 64, BATCH / 64), 256, 0, stream>>>(
        cat, aw1, ab1, h1, nullptr, HDIM, JDIM);
    // h2 = relu(joint @ hw1^T + hb1)
    sgemm_kernel<1><<<dim3(LDIM / 64, BATCH / 64), 256, 0, stream>>>(
        cat, hw1, hb1, h2, nullptr, LDIM, JDIM);
    // logits = h1 @ aw2^T + ab2 -> d_out;  ans = tanh(logits)
    sgemm_kernel<2><<<dim3(ODIM / 64, BATCH / 64), 256, 0, stream>>>(
        h1, aw2, ab2, logits_out + (size_t)s * BATCH * ODIM, ans, ODIM, HDIM);
    // halt = h2 @ hw2^T + hb2 -> d_out
    halt_kernel<<<BATCH / 4, 256, 0, stream>>>(
        h2, hw2, hb2, halt_out + (size_t)s * BATCH * 2);
  }
}

// Round 2
// 6121.878 us; speedup vs baseline: 3.1814x; 3.1814x over previous
//
#include <hip/hip_runtime.h>
#include <math.h>

#define BATCH 4096
#define LDIM 1024
#define HDIM 2048
#define ODIM 512
#define GDIM 3072   // 3*LDIM
#define JDIM 1536   // IDIM+ODIM == LDIM+ODIM
#define INNER 4
#define OUTER 8

typedef unsigned short ushort_t;
using bf16x8 = __attribute__((ext_vector_type(8))) short;
using f32x4 = __attribute__((ext_vector_type(4))) float;

typedef __attribute__((address_space(3))) void lds_void;
typedef __attribute__((address_space(1))) void glob_void;

__device__ __forceinline__ void gload16(const void* g, void* l) {
  __builtin_amdgcn_global_load_lds((const glob_void*)g, (lds_void*)l, 16, 0, 0);
}

__device__ __forceinline__ ushort_t f2bf(float x) {
  unsigned u = __builtin_bit_cast(unsigned, x);
  unsigned r = (u + 0x7FFFu + ((u >> 16) & 1u)) >> 16;
  return (ushort_t)r;
}
__device__ __forceinline__ float bf2f(ushort_t h) {
  unsigned u = ((unsigned)h) << 16;
  return __builtin_bit_cast(float, u);
}
__device__ __forceinline__ float sigmoidf_(float x) {
  return 1.0f / (1.0f + expf(-x));
}
__device__ __forceinline__ void split_bf(float v, ushort_t& h, ushort_t& l) {
  h = f2bf(v);
  l = f2bf(v - bf2f(h));
}

// fp32 -> (hi, lo) bf16 pair, n4 = elems/4
__global__ __launch_bounds__(256) void convert_pair(
    const float* __restrict__ src, ushort_t* __restrict__ hi,
    ushort_t* __restrict__ lo, int n4) {
  int i = blockIdx.x * 256 + threadIdx.x;
  if (i >= n4) return;
  float4 v = ((const float4*)src)[i];
  ushort4 h, l;
  split_bf(v.x, h.x, l.x);
  split_bf(v.y, h.y, l.y);
  split_bf(v.z, h.z, l.z);
  split_bf(v.w, h.w, l.w);
  ((ushort4*)hi)[i] = h;
  ((ushort4*)lo)[i] = l;
}

// cat = [a (B,1024) | b (B,512)] -> bf16 pair [B,1536]
__global__ __launch_bounds__(256) void concat_convert(
    const float* __restrict__ a, const float* __restrict__ b,
    ushort_t* __restrict__ hi, ushort_t* __restrict__ lo) {
  int idx = blockIdx.x * 256 + threadIdx.x;
  const int C4 = JDIM / 4;  // 384
  if (idx >= BATCH * C4) return;
  int row = idx / C4;
  int c4 = idx - row * C4;
  float4 v;
  if (c4 < 256)
    v = ((const float4*)a)[row * 256 + c4];
  else
    v = ((const float4*)b)[row * 128 + (c4 - 256)];
  ushort4 h, l;
  split_bf(v.x, h.x, l.x);
  split_bf(v.y, h.y, l.y);
  split_bf(v.z, h.z, l.z);
  split_bf(v.w, h.w, l.w);
  ((ushort4*)hi)[idx] = h;
  ((ushort4*)lo)[idx] = l;
}

// ============================================================================
// bf16x2 split MFMA GEMM: C[M=4096, N] = epi(A @ W^T + bias)
// A given as (Ah, Al) [M][K] bf16; W as (Wh, Wl) [N][K] bf16. K%32==0, N%128==0.
// Tile 128x128, BK=32, 256 thr = 4 waves (2x2), wave tile 64x64 = 4x4 frags.
// EPI: 0 = fp32 C
//      1 = relu -> fp32 C
//      2 = relu -> bf16 pair (Ch, Cl)
//      3 = fp32 C (pre-act) + tanh -> fp32 C2
// ============================================================================
template <int EPI>
__global__ __launch_bounds__(256, 2) void mfma_gemm(
    const ushort_t* __restrict__ Ah, const ushort_t* __restrict__ Al,
    const ushort_t* __restrict__ Wh, const ushort_t* __restrict__ Wl,
    const float* __restrict__ bias, float* __restrict__ C,
    float* __restrict__ C2, ushort_t* __restrict__ Ch,
    ushort_t* __restrict__ Cl, int N, int K) {
  __shared__ ushort_t sAh[128 * 32];
  __shared__ ushort_t sAl[128 * 32];
  __shared__ ushort_t sWh[128 * 32];
  __shared__ ushort_t sWl[128 * 32];

  const int tid = threadIdx.x;
  const int w = tid >> 6;       // wave 0..3
  const int lane = tid & 63;
  const int wm = w >> 1;        // wave row (0..1)
  const int wn = w & 1;         // wave col (0..1)
  const int fr = lane & 15;
  const int quad = lane >> 4;
  const int n0 = blockIdx.x * 128;
  const int m0 = blockIdx.y * 128;

  // staging: wave w covers rows [w*32, w*32+32) of each 128x32 tile,
  // two 16-row chunks; lane l -> row base + l/4, col (l&3)*8 elems.
  const int srow = w * 32 + (lane >> 2);
  const int scol = (lane & 3) * 8;
  const ushort_t* pAh = Ah + (size_t)(m0 + srow) * K + scol;
  const ushort_t* pAl = Al + (size_t)(m0 + srow) * K + scol;
  const ushort_t* pWh = Wh + (size_t)(n0 + srow) * K + scol;
  const ushort_t* pWl = Wl + (size_t)(n0 + srow) * K + scol;
  const size_t rstep = (size_t)16 * K;  // 16 rows
  ushort_t* lAh = &sAh[w * 1024];
  ushort_t* lAl = &sAl[w * 1024];
  ushort_t* lWh = &sWh[w * 1024];
  ushort_t* lWl = &sWl[w * 1024];

  f32x4 acc[4][4] = {};

  for (int k0 = 0; k0 < K; k0 += 32) {
    __syncthreads();  // previous tile fully consumed
    gload16(pAh + k0, lAh);
    gload16(pAh + rstep + k0, lAh + 512);
    gload16(pAl + k0, lAl);
    gload16(pAl + rstep + k0, lAl + 512);
    gload16(pWh + k0, lWh);
    gload16(pWh + rstep + k0, lWh + 512);
    gload16(pWl + k0, lWl);
    gload16(pWl + rstep + k0, lWl + 512);
    __syncthreads();  // loads landed (barrier drains vmcnt)

    bf16x8 ah[4], al[4], bh[4], bl[4];
#pragma unroll
    for (int i = 0; i < 4; ++i) {
      int r = (wm * 64 + i * 16 + fr) * 32 + quad * 8;
      ah[i] = *(const bf16x8*)&sAh[r];
      al[i] = *(const bf16x8*)&sAl[r];
    }
#pragma unroll
    for (int j = 0; j < 4; ++j) {
      int r = (wn * 64 + j * 16 + fr) * 32 + quad * 8;
      bh[j] = *(const bf16x8*)&sWh[r];
      bl[j] = *(const bf16x8*)&sWl[r];
    }
#pragma unroll
    for (int i = 0; i < 4; ++i)
#pragma unroll
      for (int j = 0; j < 4; ++j) {
        acc[i][j] = __builtin_amdgcn_mfma_f32_16x16x32_bf16(ah[i], bh[j], acc[i][j], 0, 0, 0);
        acc[i][j] = __builtin_amdgcn_mfma_f32_16x16x32_bf16(ah[i], bl[j], acc[i][j], 0, 0, 0);
        acc[i][j] = __builtin_amdgcn_mfma_f32_16x16x32_bf16(al[i], bh[j], acc[i][j], 0, 0, 0);
      }
  }

  // epilogue. C/D map: col = lane&15, row = quad*4 + reg
#pragma unroll
  for (int j = 0; j < 4; ++j) {
    int n = n0 + wn * 64 + j * 16 + fr;
    float bv = bias[n];
#pragma unroll
    for (int i = 0; i < 4; ++i) {
#pragma unroll
      for (int r = 0; r < 4; ++r) {
        int m = m0 + wm * 64 + i * 16 + quad * 4 + r;
        float v = acc[i][j][r] + bv;
        size_t o = (size_t)m * N + n;
        if (EPI == 0) {
          C[o] = v;
        } else if (EPI == 1) {
          C[o] = fmaxf(v, 0.0f);
        } else if (EPI == 2) {
          float vr = fmaxf(v, 0.0f);
          ushort_t h, l;
          split_bf(vr, h, l);
          Ch[o] = h;
          Cl[o] = l;
        } else {
          C[o] = v;
          C2[o] = tanhf(v);
        }
      }
    }
  }
}

// elementwise GRU gate update, in-place state. xg/hg already include biases.
__global__ __launch_bounds__(256) void gru_ew(
    const float* __restrict__ xg, const float* __restrict__ hg,
    float* __restrict__ stateF, ushort_t* __restrict__ stateH,
    ushort_t* __restrict__ stateL) {
  int idx = blockIdx.x * 256 + threadIdx.x;  // over B*1024/4
  if (idx >= BATCH * (LDIM / 4)) return;
  int m = idx >> 8;          // /256
  int l4 = idx & 255;
  size_t gbase = (size_t)m * GDIM + l4 * 4;
  float4 xr = *(const float4*)&xg[gbase];
  float4 xz = *(const float4*)&xg[gbase + LDIM];
  float4 xn = *(const float4*)&xg[gbase + 2 * LDIM];
  float4 hr = *(const float4*)&hg[gbase];
  float4 hz = *(const float4*)&hg[gbase + LDIM];
  float4 hn = *(const float4*)&hg[gbase + 2 * LDIM];
  float4 s = ((const float4*)stateF)[idx];
  float xrv[4] = {xr.x, xr.y, xr.z, xr.w}, xzv[4] = {xz.x, xz.y, xz.z, xz.w};
  float xnv[4] = {xn.x, xn.y, xn.z, xn.w}, hrv[4] = {hr.x, hr.y, hr.z, hr.w};
  float hzv[4] = {hz.x, hz.y, hz.z, hz.w}, hnv[4] = {hn.x, hn.y, hn.z, hn.w};
  float sv[4] = {s.x, s.y, s.z, s.w};
  float o[4];
  ushort4 oh, ol;
  ushort_t* ph = (ushort_t*)&oh;
  ushort_t* pl = (ushort_t*)&ol;
#pragma unroll
  for (int k = 0; k < 4; ++k) {
    float r = sigmoidf_(xrv[k] + hrv[k]);
    float z = sigmoidf_(xzv[k] + hzv[k]);
    float n = tanhf(xnv[k] + r * hnv[k]);
    o[k] = (1.0f - z) * n + z * sv[k];
    split_bf(o[k], ph[k], pl[k]);
  }
  float4 ov = {o[0], o[1], o[2], o[3]};
  ((float4*)stateF)[idx] = ov;
  ((ushort4*)stateH)[idx] = oh;
  ((ushort4*)stateL)[idx] = ol;
}

// halt = h2[B,1024] @ hw2[2,1024]^T + hb2; one wave per row.
__global__ __launch_bounds__(256) void halt_kernel(
    const float* __restrict__ h2, const float* __restrict__ hw2,
    const float* __restrict__ hb2, float* __restrict__ out) {
  int wave = (blockIdx.x * 256 + threadIdx.x) >> 6;
  int lane = threadIdx.x & 63;
  if (wave >= BATCH) return;
  const float* row = h2 + (size_t)wave * LDIM;
  float s0 = 0.0f, s1 = 0.0f;
#pragma unroll
  for (int k = lane; k < LDIM; k += 64) {
    float v = row[k];
    s0 = fmaf(v, hw2[k], s0);
    s1 = fmaf(v, hw2[LDIM + k], s1);
  }
#pragma unroll
  for (int off = 32; off > 0; off >>= 1) {
    s0 += __shfl_xor(s0, off);
    s1 += __shfl_xor(s1, off);
  }
  if (lane == 0) {
    out[(size_t)wave * 2 + 0] = s0 + hb2[0];
    out[(size_t)wave * 2 + 1] = s1 + hb2[1];
  }
}

extern "C" void kernel_launch(void* const* d_in, const int* in_sizes, int n_in,
                              void* d_out, int out_size, void* d_ws, size_t ws_size,
                              hipStream_t stream) {
  const float* inputs = (const float*)d_in[0];
  const float* W_ih = (const float*)d_in[1];
  const float* W_hh = (const float*)d_in[2];
  const float* b_ih = (const float*)d_in[3];
  const float* b_hh = (const float*)d_in[4];
  const float* aw1 = (const float*)d_in[5];
  const float* ab1 = (const float*)d_in[6];
  const float* aw2 = (const float*)d_in[7];
  const float* ab2 = (const float*)d_in[8];
  const float* hw1 = (const float*)d_in[9];
  const float* hb1 = (const float*)d_in[10];
  const float* hw2 = (const float*)d_in[11];
  const float* hb2 = (const float*)d_in[12];

  float* out = (float*)d_out;
  float* logits_out = out;                               // [8, B, 512]
  float* halt_out = out + (size_t)OUTER * BATCH * ODIM;  // [8, B, 2]

  // ---- workspace layout (bytes) ----
  char* p = (char*)d_ws;
  auto take = [&](size_t bytes) { char* q = p; p += bytes; return q; };
  float* stateF = (float*)take((size_t)BATCH * LDIM * 4);      // 16.8 MB
  float* ans = (float*)take((size_t)BATCH * ODIM * 4);         // 8.4 MB
  ushort_t* stateH = (ushort_t*)take((size_t)BATCH * LDIM * 2);
  ushort_t* stateL = (ushort_t*)take((size_t)BATCH * LDIM * 2);
  ushort_t* catH = (ushort_t*)take((size_t)BATCH * JDIM * 2);
  ushort_t* catL = (ushort_t*)take((size_t)BATCH * JDIM * 2);
  float* xg = (float*)take((size_t)BATCH * GDIM * 4);          // 50.3 MB
  float* hg = (float*)take((size_t)BATCH * GDIM * 4);          // 50.3 MB
  ushort_t* WihH = (ushort_t*)take((size_t)GDIM * JDIM * 2);
  ushort_t* WihL = (ushort_t*)take((size_t)GDIM * JDIM * 2);
  ushort_t* WhhH = (ushort_t*)take((size_t)GDIM * LDIM * 2);
  ushort_t* WhhL = (ushort_t*)take((size_t)GDIM * LDIM * 2);
  ushort_t* aw1H = (ushort_t*)take((size_t)HDIM * JDIM * 2);
  ushort_t* aw1L = (ushort_t*)take((size_t)HDIM * JDIM * 2);
  ushort_t* aw2H = (ushort_t*)take((size_t)ODIM * HDIM * 2);
  ushort_t* aw2L = (ushort_t*)take((size_t)ODIM * HDIM * 2);
  ushort_t* hw1H = (ushort_t*)take((size_t)LDIM * JDIM * 2);
  ushort_t* hw1L = (ushort_t*)take((size_t)LDIM * JDIM * 2);
  // overlays (dead regions reused within a step):
  ushort_t* h1H = (ushort_t*)hg;                                // 16.8 MB
  ushort_t* h1L = (ushort_t*)((char*)hg + (size_t)BATCH * HDIM * 2);
  float* h2F = xg;                                              // 16.8 MB

  // zero initial state / ans (incl. bf16 pair of state)
  hipMemsetAsync(stateF, 0, (size_t)BATCH * LDIM * 4, stream);
  hipMemsetAsync(stateH, 0, (size_t)BATCH * LDIM * 2, stream);
  hipMemsetAsync(stateL, 0, (size_t)BATCH * LDIM * 2, stream);
  hipMemsetAsync(ans, 0, (size_t)BATCH * ODIM * 4, stream);

  // weight conversion (weights restored by harness each call)
  auto conv = [&](const float* s, ushort_t* h, ushort_t* l, size_t n) {
    int n4 = (int)(n / 4);
    convert_pair<<<(n4 + 255) / 256, 256, 0, stream>>>(s, h, l, n4);
  };
  conv(W_ih, WihH, WihL, (size_t)GDIM * JDIM);
  conv(W_hh, WhhH, WhhL, (size_t)GDIM * LDIM);
  conv(aw1, aw1H, aw1L, (size_t)HDIM * JDIM);
  conv(aw2, aw2H, aw2L, (size_t)ODIM * HDIM);
  conv(hw1, hw1H, hw1L, (size_t)LDIM * JDIM);

  const int cat_blocks = (BATCH * (JDIM / 4) + 255) / 256;
  const int ew_blocks = (BATCH * (LDIM / 4) + 255) / 256;

  for (int s = 0; s < OUTER; ++s) {
    // x = [inputs | ans] -> bf16 pair; x_gates = x @ W_ih^T + b_ih (fp32)
    concat_convert<<<cat_blocks, 256, 0, stream>>>(inputs, ans, catH, catL);
    mfma_gemm<0><<<dim3(GDIM / 128, BATCH / 128), 256, 0, stream>>>(
        catH, catL, WihH, WihL, b_ih, xg, nullptr, nullptr, nullptr, GDIM, JDIM);
    // 4 GRU cycles: h_gates GEMM + elementwise update
    for (int c = 0; c < INNER; ++c) {
      mfma_gemm<0><<<dim3(GDIM / 128, BATCH / 128), 256, 0, stream>>>(
          stateH, stateL, WhhH, WhhL, b_hh, hg, nullptr, nullptr, nullptr, GDIM, LDIM);
      gru_ew<<<ew_blocks, 256, 0, stream>>>(xg, hg, stateF, stateH, stateL);
    }
    // joint = [state | ans] -> bf16 pair
    concat_convert<<<cat_blocks, 256, 0, stream>>>(stateF, ans, catH, catL);
    // h1 = relu(joint @ aw1^T + ab1) -> bf16 pair (overlays hg; hg dead now)
    mfma_gemm<2><<<dim3(HDIM / 128, BATCH / 128), 256, 0, stream>>>(
        catH, catL, aw1H, aw1L, ab1, nullptr, nullptr, h1H, h1L, HDIM, JDIM);
    // h2 = relu(joint @ hw1^T + hb1) -> fp32 (overlays xg; xg dead now)
    mfma_gemm<1><<<dim3(LDIM / 128, BATCH / 128), 256, 0, stream>>>(
        catH, catL, hw1H, hw1L, hb1, h2F, nullptr, nullptr, nullptr, LDIM, JDIM);
    // logits = h1 @ aw2^T + ab2 -> out; ans = tanh(logits)
    mfma_gemm<3><<<dim3(ODIM / 128, BATCH / 128), 256, 0, stream>>>(
        h1H, h1L, aw2H, aw2L, ab2, logits_out + (size_t)s * BATCH * ODIM, ans,
        nullptr, nullptr, ODIM, HDIM);
    // halt = h2 @ hw2^T + hb2 -> out
    halt_kernel<<<BATCH / 4, 256, 0, stream>>>(
        h2F, hw2, hb2, halt_out + (size_t)s * BATCH * 2);
  }
}

// Round 4
// 4824.494 us; speedup vs baseline: 4.0369x; 1.2689x over previous
//
#include <hip/hip_runtime.h>
#include <math.h>

#define BATCH 4096
#define LDIM 1024
#define HDIM 2048
#define ODIM 512
#define GDIM 3072   // 3*LDIM
#define JDIM 1536   // IDIM+ODIM == LDIM+ODIM
#define INNER 4
#define OUTER 8

using f16 = _Float16;
using f16x4 = __attribute__((ext_vector_type(4))) _Float16;
using f16x8 = __attribute__((ext_vector_type(8))) _Float16;
using f32x4 = __attribute__((ext_vector_type(4))) float;

typedef __attribute__((address_space(3))) void lds_void;
typedef __attribute__((address_space(1))) void glob_void;

__device__ __forceinline__ void gload16(const void* g, void* l) {
  __builtin_amdgcn_global_load_lds((const glob_void*)g, (lds_void*)l, 16, 0, 0);
}

#define MFMA16(a, b, c) __builtin_amdgcn_mfma_f32_16x16x32_f16(a, b, c, 0, 0, 0)

__device__ __forceinline__ float sigmoidf_(float x) {
  return 1.0f / (1.0f + expf(-x));
}
// fp32 -> fp16 (hi, lo): hi+lo represents v to ~22 bits
__device__ __forceinline__ void split_h(float v, f16& h, f16& l) {
  h = (f16)v;
  l = (f16)(v - (float)h);
}

// fp32 -> single fp16 (RTN), n4 = elems/4
__global__ __launch_bounds__(256) void convert_w(const float* __restrict__ src,
                                                 f16* __restrict__ dst, int n4) {
  int i = blockIdx.x * 256 + threadIdx.x;
  if (i >= n4) return;
  float4 v = ((const float4*)src)[i];
  f16x4 d = {(f16)v.x, (f16)v.y, (f16)v.z, (f16)v.w};
  *(f16x4*)&dst[(size_t)i * 4] = d;
}

// inputs [B,1024] fp32 -> cols [0,1024) of catX pair [B,1536]
__global__ __launch_bounds__(256) void input_to_cat(
    const float* __restrict__ inp, f16* __restrict__ cH, f16* __restrict__ cL) {
  int idx = blockIdx.x * 256 + threadIdx.x;  // over B*256 float4s
  if (idx >= BATCH * 256) return;
  int row = idx >> 8, c4 = idx & 255;
  float4 v = ((const float4*)inp)[idx];
  float vv[4] = {v.x, v.y, v.z, v.w};
  f16 hv[4], lv[4];
#pragma unroll
  for (int k = 0; k < 4; ++k) split_h(vv[k], hv[k], lv[k]);
  f16x4 h4 = {hv[0], hv[1], hv[2], hv[3]};
  f16x4 l4 = {lv[0], lv[1], lv[2], lv[3]};
  size_t o = (size_t)row * JDIM + c4 * 4;
  *(f16x4*)&cH[o] = h4;
  *(f16x4*)&cL[o] = l4;
}

// ============================================================================
// fp16-split GEMM: C[4096, N] = epi(A @ W^T + bias)
// A = (Ah + Al) fp16 pair [M][K]; W single fp16 [N][K]. K%32==0, N%128==0.
// Tile 128x128, BK=32, 4 waves (2x2), wave 64x64 = 4x4 frags, 2 MFMA/frag.
// EPI: 0 = fp32 C          1 = relu -> fp32 C
//      2 = relu -> fp16 pair (ChH, ChL)
//      3 = fp32 C (N=512) + tanh -> fp16 pair into catX & catJ ans-columns
// ============================================================================
template <int EPI>
__global__ __launch_bounds__(256, 2) void gemm_f16s(
    const f16* __restrict__ Ah, const f16* __restrict__ Al,
    const f16* __restrict__ W, const float* __restrict__ bias,
    float* __restrict__ Cf, f16* __restrict__ ChH, f16* __restrict__ ChL,
    f16* __restrict__ aXH, f16* __restrict__ aXL,
    f16* __restrict__ aJH, f16* __restrict__ aJL, int N, int K) {
  __shared__ f16 sAh[128 * 32];
  __shared__ f16 sAl[128 * 32];
  __shared__ f16 sW[128 * 32];
  const int tid = threadIdx.x;
  const int w = tid >> 6, lane = tid & 63;
  const int wm = w >> 1, wn = w & 1;
  const int fr = lane & 15, quad = lane >> 4;
  const int m0 = blockIdx.y * 128, n0 = blockIdx.x * 128;
  const int srow = w * 32 + (lane >> 2);
  const int scol = (lane & 3) * 8;
  const f16* pAh = Ah + (size_t)(m0 + srow) * K + scol;
  const f16* pAl = Al + (size_t)(m0 + srow) * K + scol;
  const f16* pW = W + (size_t)(n0 + srow) * K + scol;
  const size_t rstep = (size_t)16 * K;
  f16* lAh = &sAh[w * 1024];
  f16* lAl = &sAl[w * 1024];
  f16* lW = &sW[w * 1024];

  f32x4 acc[4][4] = {};
  for (int k0 = 0; k0 < K; k0 += 32) {
    __syncthreads();
    gload16(pAh + k0, lAh);
    gload16(pAh + rstep + k0, lAh + 512);
    gload16(pAl + k0, lAl);
    gload16(pAl + rstep + k0, lAl + 512);
    gload16(pW + k0, lW);
    gload16(pW + rstep + k0, lW + 512);
    __syncthreads();
    f16x8 ah[4], al[4], bw[4];
#pragma unroll
    for (int i = 0; i < 4; ++i) {
      int r = (wm * 64 + i * 16 + fr) * 32 + quad * 8;
      ah[i] = *(const f16x8*)&sAh[r];
      al[i] = *(const f16x8*)&sAl[r];
    }
#pragma unroll
    for (int j = 0; j < 4; ++j) {
      int r = (wn * 64 + j * 16 + fr) * 32 + quad * 8;
      bw[j] = *(const f16x8*)&sW[r];
    }
#pragma unroll
    for (int i = 0; i < 4; ++i)
#pragma unroll
      for (int j = 0; j < 4; ++j) {
        acc[i][j] = MFMA16(ah[i], bw[j], acc[i][j]);
        acc[i][j] = MFMA16(al[i], bw[j], acc[i][j]);
      }
  }
  // C/D map: col = lane&15, row = quad*4 + reg
#pragma unroll
  for (int j = 0; j < 4; ++j) {
    int n = n0 + wn * 64 + j * 16 + fr;
    float bv = bias[n];
#pragma unroll
    for (int i = 0; i < 4; ++i) {
#pragma unroll
      for (int r = 0; r < 4; ++r) {
        int m = m0 + wm * 64 + i * 16 + quad * 4 + r;
        float v = acc[i][j][r] + bv;
        if (EPI == 0) {
          Cf[(size_t)m * N + n] = v;
        } else if (EPI == 1) {
          Cf[(size_t)m * N + n] = fmaxf(v, 0.0f);
        } else if (EPI == 2) {
          float vr = fmaxf(v, 0.0f);
          f16 h, l;
          split_h(vr, h, l);
          ChH[(size_t)m * N + n] = h;
          ChL[(size_t)m * N + n] = l;
        } else {
          Cf[(size_t)m * N + n] = v;
          float t = tanhf(v);
          f16 h, l;
          split_h(t, h, l);
          size_t c = (size_t)m * JDIM + 1024 + n;
          aXH[c] = h; aXL[c] = l;
          aJH[c] = h; aJL[c] = l;
        }
      }
    }
  }
}

// ============================================================================
// Fused GRU cycle: h_gates = state @ W_hh^T + b_hh for r,z,n + gate update.
// Block tile: 128(M) x 64(N per gate) x 3 gates. 4 waves, wave = 32(M)x64(N).
// state in/out as fp16 pairs (ping-pong). Last cycle also writes catJ state cols.
// ============================================================================
__global__ __launch_bounds__(256, 2) void gru_fused(
    const f16* __restrict__ inH, const f16* __restrict__ inL,
    const f16* __restrict__ Whh, const float* __restrict__ bhh,
    const float* __restrict__ xg, f16* __restrict__ outH,
    f16* __restrict__ outL, f16* __restrict__ catJH, f16* __restrict__ catJL) {
  __shared__ f16 sAh[128 * 32];
  __shared__ f16 sAl[128 * 32];
  __shared__ f16 sW0[64 * 32];
  __shared__ f16 sW1[64 * 32];
  __shared__ f16 sW2[64 * 32];
  const int tid = threadIdx.x;
  const int w = tid >> 6, lane = tid & 63;
  const int fr = lane & 15, quad = lane >> 4;
  const int n0 = blockIdx.x * 64, m0 = blockIdx.y * 128;
  const int srow = w * 32 + (lane >> 2);
  const int scol = (lane & 3) * 8;
  const f16* pAh = inH + (size_t)(m0 + srow) * LDIM + scol;
  const f16* pAl = inL + (size_t)(m0 + srow) * LDIM + scol;
  const size_t rstepA = (size_t)16 * LDIM;
  const int wrow = w * 16 + (lane >> 2);
  const f16* pW0 = Whh + (size_t)(n0 + wrow) * LDIM + scol;
  const f16* pW1 = pW0 + (size_t)LDIM * LDIM;
  const f16* pW2 = pW1 + (size_t)LDIM * LDIM;
  f16* lAh = &sAh[w * 1024];
  f16* lAl = &sAl[w * 1024];
  f16* lW0 = &sW0[w * 512];
  f16* lW1 = &sW1[w * 512];
  f16* lW2 = &sW2[w * 512];

  f32x4 ar[2][4] = {}, az[2][4] = {}, an_[2][4] = {};
  for (int k0 = 0; k0 < LDIM; k0 += 32) {
    __syncthreads();
    gload16(pAh + k0, lAh);
    gload16(pAh + rstepA + k0, lAh + 512);
    gload16(pAl + k0, lAl);
    gload16(pAl + rstepA + k0, lAl + 512);
    gload16(pW0 + k0, lW0);
    gload16(pW1 + k0, lW1);
    gload16(pW2 + k0, lW2);
    __syncthreads();
    f16x8 a_h[2], a_l[2], w0[4], w1[4], w2[4];
#pragma unroll
    for (int i = 0; i < 2; ++i) {
      int r = (w * 32 + i * 16 + fr) * 32 + quad * 8;
      a_h[i] = *(const f16x8*)&sAh[r];
      a_l[i] = *(const f16x8*)&sAl[r];
    }
#pragma unroll
    for (int j = 0; j < 4; ++j) {
      int r = (j * 16 + fr) * 32 + quad * 8;
      w0[j] = *(const f16x8*)&sW0[r];
      w1[j] = *(const f16x8*)&sW1[r];
      w2[j] = *(const f16x8*)&sW2[r];
    }
#pragma unroll
    for (int i = 0; i < 2; ++i)
#pragma unroll
      for (int j = 0; j < 4; ++j) {
        ar[i][j] = MFMA16(a_h[i], w0[j], ar[i][j]);
        ar[i][j] = MFMA16(a_l[i], w0[j], ar[i][j]);
        az[i][j] = MFMA16(a_h[i], w1[j], az[i][j]);
        az[i][j] = MFMA16(a_l[i], w1[j], az[i][j]);
        an_[i][j] = MFMA16(a_h[i], w2[j], an_[i][j]);
        an_[i][j] = MFMA16(a_l[i], w2[j], an_[i][j]);
      }
  }
  // epilogue: full GRU gate update
#pragma unroll
  for (int j = 0; j < 4; ++j) {
    int col = n0 + j * 16 + fr;
    float br = bhh[col], bz = bhh[col + LDIM], bn = bhh[col + 2 * LDIM];
#pragma unroll
    for (int i = 0; i < 2; ++i) {
#pragma unroll
      for (int r = 0; r < 4; ++r) {
        int m = m0 + w * 32 + i * 16 + quad * 4 + r;
        size_t xb = (size_t)m * GDIM + col;
        float xr = xg[xb], xz = xg[xb + LDIM], xn = xg[xb + 2 * LDIM];
        size_t si = (size_t)m * LDIM + col;
        float sold = (float)inH[si] + (float)inL[si];
        float rg = sigmoidf_(xr + ar[i][j][r] + br);
        float zg = sigmoidf_(xz + az[i][j][r] + bz);
        float ng = tanhf(xn + rg * (an_[i][j][r] + bn));
        float o = (1.0f - zg) * ng + zg * sold;
        f16 h, l;
        split_h(o, h, l);
        outH[si] = h;
        outL[si] = l;
        if (catJH) {
          size_t ci = (size_t)m * JDIM + col;
          catJH[ci] = h;
          catJL[ci] = l;
        }
      }
    }
  }
}

// halt = h2[B,1024] @ hw2[2,1024]^T + hb2; one wave per row.
__global__ __launch_bounds__(256) void halt_kernel(
    const float* __restrict__ h2, const float* __restrict__ hw2,
    const float* __restrict__ hb2, float* __restrict__ out) {
  int wave = (blockIdx.x * 256 + threadIdx.x) >> 6;
  int lane = threadIdx.x & 63;
  if (wave >= BATCH) return;
  const float* row = h2 + (size_t)wave * LDIM;
  float s0 = 0.0f, s1 = 0.0f;
#pragma unroll
  for (int k = lane; k < LDIM; k += 64) {
    float v = row[k];
    s0 = fmaf(v, hw2[k], s0);
    s1 = fmaf(v, hw2[LDIM + k], s1);
  }
#pragma unroll
  for (int off = 32; off > 0; off >>= 1) {
    s0 += __shfl_xor(s0, off);
    s1 += __shfl_xor(s1, off);
  }
  if (lane == 0) {
    out[(size_t)wave * 2 + 0] = s0 + hb2[0];
    out[(size_t)wave * 2 + 1] = s1 + hb2[1];
  }
}

extern "C" void kernel_launch(void* const* d_in, const int* in_sizes, int n_in,
                              void* d_out, int out_size, void* d_ws, size_t ws_size,
                              hipStream_t stream) {
  const float* inputs = (const float*)d_in[0];
  const float* W_ih = (const float*)d_in[1];
  const float* W_hh = (const float*)d_in[2];
  const float* b_ih = (const float*)d_in[3];
  const float* b_hh = (const float*)d_in[4];
  const float* aw1 = (const float*)d_in[5];
  const float* ab1 = (const float*)d_in[6];
  const float* aw2 = (const float*)d_in[7];
  const float* ab2 = (const float*)d_in[8];
  const float* hw1 = (const float*)d_in[9];
  const float* hb1 = (const float*)d_in[10];
  const float* hw2 = (const float*)d_in[11];
  const float* hb2 = (const float*)d_in[12];

  float* out = (float*)d_out;
  float* logits_out = out;                               // [8, B, 512]
  float* halt_out = out + (size_t)OUTER * BATCH * ODIM;  // [8, B, 2]

  char* p = (char*)d_ws;
  auto take = [&](size_t bytes) { char* q = p; p += (bytes + 255) & ~255ull; return q; };
  f16* stAH = (f16*)take((size_t)BATCH * LDIM * 2);
  f16* stAL = (f16*)take((size_t)BATCH * LDIM * 2);
  f16* stBH = (f16*)take((size_t)BATCH * LDIM * 2);
  f16* stBL = (f16*)take((size_t)BATCH * LDIM * 2);
  f16* catXH = (f16*)take((size_t)BATCH * JDIM * 2);
  f16* catXL = (f16*)take((size_t)BATCH * JDIM * 2);
  f16* catJH = (f16*)take((size_t)BATCH * JDIM * 2);
  f16* catJL = (f16*)take((size_t)BATCH * JDIM * 2);
  float* xg = (float*)take((size_t)BATCH * GDIM * 4);   // 50 MB
  float* h2F = (float*)take((size_t)BATCH * LDIM * 4);
  f16* WihF = (f16*)take((size_t)GDIM * JDIM * 2);
  f16* WhhF = (f16*)take((size_t)GDIM * LDIM * 2);
  f16* aw1F = (f16*)take((size_t)HDIM * JDIM * 2);
  f16* aw2F = (f16*)take((size_t)ODIM * HDIM * 2);
  f16* hw1F = (f16*)take((size_t)LDIM * JDIM * 2);
  // overlay: h1 pair lives in xg region (xg dead after the GRU cycles,
  // h1 dead before next step's xg GEMM writes xg)
  f16* h1H = (f16*)xg;
  f16* h1L = h1H + (size_t)BATCH * HDIM;

  // zero init: state A pair, ans-columns of catX/catJ (whole buffers)
  (void)hipMemsetAsync(stAH, 0, (size_t)BATCH * LDIM * 2, stream);
  (void)hipMemsetAsync(stAL, 0, (size_t)BATCH * LDIM * 2, stream);
  (void)hipMemsetAsync(catXH, 0, (size_t)BATCH * JDIM * 2, stream);
  (void)hipMemsetAsync(catXL, 0, (size_t)BATCH * JDIM * 2, stream);
  (void)hipMemsetAsync(catJH, 0, (size_t)BATCH * JDIM * 2, stream);
  (void)hipMemsetAsync(catJL, 0, (size_t)BATCH * JDIM * 2, stream);

  auto conv = [&](const float* s, f16* d, size_t n) {
    int n4 = (int)(n / 4);
    convert_w<<<(n4 + 255) / 256, 256, 0, stream>>>(s, d, n4);
  };
  conv(W_ih, WihF, (size_t)GDIM * JDIM);
  conv(W_hh, WhhF, (size_t)GDIM * LDIM);
  conv(aw1, aw1F, (size_t)HDIM * JDIM);
  conv(aw2, aw2F, (size_t)ODIM * HDIM);
  conv(hw1, hw1F, (size_t)LDIM * JDIM);
  input_to_cat<<<BATCH, 256, 0, stream>>>(inputs, catXH, catXL);

  for (int s = 0; s < OUTER; ++s) {
    // x_gates = [inputs|ans] @ W_ih^T + b_ih -> fp32 xg
    gemm_f16s<0><<<dim3(GDIM / 128, BATCH / 128), 256, 0, stream>>>(
        catXH, catXL, WihF, b_ih, xg, nullptr, nullptr,
        nullptr, nullptr, nullptr, nullptr, GDIM, JDIM);
    // 4 fused GRU cycles, ping-pong; last writes catJ state cols
    f16 *curH = stAH, *curL = stAL, *nxtH = stBH, *nxtL = stBL;
    for (int c = 0; c < INNER; ++c) {
      bool last = (c == INNER - 1);
      gru_fused<<<dim3(LDIM / 64, BATCH / 128), 256, 0, stream>>>(
          curH, curL, WhhF, b_hh, xg, nxtH, nxtL,
          last ? catJH : nullptr, last ? catJL : nullptr);
      f16* t;
      t = curH; curH = nxtH; nxtH = t;
      t = curL; curL = nxtL; nxtL = t;
    }
    // h1 = relu(joint @ aw1^T + ab1) -> fp16 pair (overlays xg)
    gemm_f16s<2><<<dim3(HDIM / 128, BATCH / 128), 256, 0, stream>>>(
        catJH, catJL, aw1F, ab1, nullptr, h1H, h1L,
        nullptr, nullptr, nullptr, nullptr, HDIM, JDIM);
    // h2 = relu(joint @ hw1^T + hb1) -> fp32
    gemm_f16s<1><<<dim3(LDIM / 128, BATCH / 128), 256, 0, stream>>>(
        catJH, catJL, hw1F, hb1, h2F, nullptr, nullptr,
        nullptr, nullptr, nullptr, nullptr, LDIM, JDIM);
    // logits = h1 @ aw2^T + ab2 -> out; ans = tanh -> catX/catJ ans cols
    gemm_f16s<3><<<dim3(ODIM / 128, BATCH / 128), 256, 0, stream>>>(
        h1H, h1L, aw2F, ab2, logits_out + (size_t)s * BATCH * ODIM,
        nullptr, nullptr, catXH, catXL, catJH, catJL, ODIM, HDIM);
    // halt = h2 @ hw2^T + hb2 -> out
    halt_kernel<<<BATCH / 4, 256, 0, stream>>>(
        h2F, hw2, hb2, halt_out + (size_t)s * BATCH * 2);
  }
}

// Round 5
// 3246.868 us; speedup vs baseline: 5.9984x; 1.4859x over previous
//
#include <hip/hip_runtime.h>
#include <math.h>

#define BATCH 4096
#define LDIM 1024
#define HDIM 2048
#define ODIM 512
#define GDIM 3072   // 3*LDIM
#define JDIM 1536   // IDIM+ODIM == LDIM+ODIM
#define INNER 4
#define OUTER 8

using f16 = _Float16;
using f16x4 = __attribute__((ext_vector_type(4))) _Float16;
using f16x8 = __attribute__((ext_vector_type(8))) _Float16;
using f32x4 = __attribute__((ext_vector_type(4))) float;

typedef __attribute__((address_space(3))) void lds_void;
typedef __attribute__((address_space(1))) void glob_void;

__device__ __forceinline__ void gload16(const void* g, void* l) {
  __builtin_amdgcn_global_load_lds((const glob_void*)g, (lds_void*)l, 16, 0, 0);
}

#define MFMA16(a, b, c) __builtin_amdgcn_mfma_f32_16x16x32_f16(a, b, c, 0, 0, 0)

__device__ __forceinline__ float sigmoidf_(float x) {
  return 1.0f / (1.0f + expf(-x));
}

// fp32 -> fp16 (RTN), n4 = elems/4
__global__ __launch_bounds__(256) void convert_w(const float* __restrict__ src,
                                                 f16* __restrict__ dst, int n4) {
  int i = blockIdx.x * 256 + threadIdx.x;
  if (i >= n4) return;
  float4 v = ((const float4*)src)[i];
  f16x4 d = {(f16)v.x, (f16)v.y, (f16)v.z, (f16)v.w};
  *(f16x4*)&dst[(size_t)i * 4] = d;
}

// inputs [B,1024] fp32 -> cols [0,1024) of catX [B,1536] fp16
__global__ __launch_bounds__(256) void input_to_cat(
    const float* __restrict__ inp, f16* __restrict__ cH) {
  int idx = blockIdx.x * 256 + threadIdx.x;  // over B*256 float4s
  if (idx >= BATCH * 256) return;
  int row = idx >> 8, c4 = idx & 255;
  float4 v = ((const float4*)inp)[idx];
  f16x4 h4 = {(f16)v.x, (f16)v.y, (f16)v.z, (f16)v.w};
  *(f16x4*)&cH[(size_t)row * JDIM + c4 * 4] = h4;
}

// ============================================================================
// fp16 GEMM: C[4096, N] = epi(A @ W^T + bias). A fp16 [M][K], W fp16 [N][K].
// Tile 128x128, BK=32, 4 waves (2x2), wave 64x64 = 4x4 frags, 1 MFMA/frag.
// EPI: 0 = fp16 C (xg)
//      1 = combined joint head: relu; n<2048 -> h1 fp16 [m][2048] (bias),
//          n>=2048 -> h2 fp32 [m][1024] (bias2)
//      2 = logits: fp32 Cout (N=512) + tanh -> fp16 into catX/catJ ans cols
// ============================================================================
template <int EPI>
__global__ __launch_bounds__(256, 2) void gemm_f16(
    const f16* __restrict__ A, const f16* __restrict__ W,
    const float* __restrict__ bias, const float* __restrict__ bias2,
    f16* __restrict__ Ch, float* __restrict__ Cf, float* __restrict__ Cout,
    f16* __restrict__ aXH, f16* __restrict__ aJH, int N, int K) {
  __shared__ f16 sA[128 * 32];
  __shared__ f16 sW[128 * 32];
  const int tid = threadIdx.x;
  const int w = tid >> 6, lane = tid & 63;
  const int wm = w >> 1, wn = w & 1;
  const int fr = lane & 15, quad = lane >> 4;
  const int m0 = blockIdx.y * 128, n0 = blockIdx.x * 128;
  const int srow = w * 32 + (lane >> 2);
  const int scol = (lane & 3) * 8;
  const f16* pA = A + (size_t)(m0 + srow) * K + scol;
  const f16* pW = W + (size_t)(n0 + srow) * K + scol;
  const size_t rstep = (size_t)16 * K;
  f16* lA = &sA[w * 1024];
  f16* lW = &sW[w * 1024];

  f32x4 acc[4][4] = {};
  for (int k0 = 0; k0 < K; k0 += 32) {
    __syncthreads();
    gload16(pA + k0, lA);
    gload16(pA + rstep + k0, lA + 512);
    gload16(pW + k0, lW);
    gload16(pW + rstep + k0, lW + 512);
    __syncthreads();
    f16x8 af[4], bf[4];
#pragma unroll
    for (int i = 0; i < 4; ++i) {
      int r = (wm * 64 + i * 16 + fr) * 32 + quad * 8;
      af[i] = *(const f16x8*)&sA[r];
    }
#pragma unroll
    for (int j = 0; j < 4; ++j) {
      int r = (wn * 64 + j * 16 + fr) * 32 + quad * 8;
      bf[j] = *(const f16x8*)&sW[r];
    }
#pragma unroll
    for (int i = 0; i < 4; ++i)
#pragma unroll
      for (int j = 0; j < 4; ++j) acc[i][j] = MFMA16(af[i], bf[j], acc[i][j]);
  }
  // C/D map: col = lane&15, row = quad*4 + reg
  bool is_h1 = true;
  const float* bp = bias;
  int nb0 = n0;
  if (EPI == 1) {
    is_h1 = (n0 < 2048);
    bp = is_h1 ? bias : bias2;
    nb0 = is_h1 ? n0 : n0 - 2048;
  }
#pragma unroll
  for (int j = 0; j < 4; ++j) {
    int n = nb0 + wn * 64 + j * 16 + fr;
    float bv = bp[n];
#pragma unroll
    for (int i = 0; i < 4; ++i) {
#pragma unroll
      for (int r = 0; r < 4; ++r) {
        int m = m0 + wm * 64 + i * 16 + quad * 4 + r;
        float v = acc[i][j][r] + bv;
        if (EPI == 0) {
          Ch[(size_t)m * N + n] = (f16)v;
        } else if (EPI == 1) {
          float vr = fmaxf(v, 0.0f);
          if (is_h1)
            Ch[(size_t)m * HDIM + n] = (f16)vr;
          else
            Cf[(size_t)m * LDIM + n] = vr;
        } else {
          Cout[(size_t)m * N + n] = v;
          f16 t = (f16)tanhf(v);
          size_t c = (size_t)m * JDIM + 1024 + n;
          aXH[c] = t;
          aJH[c] = t;
        }
      }
    }
  }
}

// ============================================================================
// Fused GRU cycle: h_gates = state @ W_hh^T + b_hh (r,z,n) + gate update.
// Block: 128(M) x 64(N per gate) x 3 gates. 4 waves, wave = 32(M)x64(N).
// state fp16 ping-pong; xg fp16. Last cycle also writes catJ state cols.
// ============================================================================
__global__ __launch_bounds__(256, 2) void gru_fused(
    const f16* __restrict__ inH, const f16* __restrict__ Whh,
    const float* __restrict__ bhh, const f16* __restrict__ xg,
    f16* __restrict__ outH, f16* __restrict__ catJH) {
  __shared__ f16 sA[128 * 32];
  __shared__ f16 sW0[64 * 32];
  __shared__ f16 sW1[64 * 32];
  __shared__ f16 sW2[64 * 32];
  const int tid = threadIdx.x;
  const int w = tid >> 6, lane = tid & 63;
  const int fr = lane & 15, quad = lane >> 4;
  const int n0 = blockIdx.x * 64, m0 = blockIdx.y * 128;
  const int srow = w * 32 + (lane >> 2);
  const int scol = (lane & 3) * 8;
  const f16* pA = inH + (size_t)(m0 + srow) * LDIM + scol;
  const size_t rstepA = (size_t)16 * LDIM;
  const int wrow = w * 16 + (lane >> 2);
  const f16* pW0 = Whh + (size_t)(n0 + wrow) * LDIM + scol;
  const f16* pW1 = pW0 + (size_t)LDIM * LDIM;
  const f16* pW2 = pW1 + (size_t)LDIM * LDIM;
  f16* lA = &sA[w * 1024];
  f16* lW0 = &sW0[w * 512];
  f16* lW1 = &sW1[w * 512];
  f16* lW2 = &sW2[w * 512];

  f32x4 ar[2][4] = {}, az[2][4] = {}, an_[2][4] = {};
  for (int k0 = 0; k0 < LDIM; k0 += 32) {
    __syncthreads();
    gload16(pA + k0, lA);
    gload16(pA + rstepA + k0, lA + 512);
    gload16(pW0 + k0, lW0);
    gload16(pW1 + k0, lW1);
    gload16(pW2 + k0, lW2);
    __syncthreads();
    f16x8 a_[2], w0[4], w1[4], w2[4];
#pragma unroll
    for (int i = 0; i < 2; ++i) {
      int r = (w * 32 + i * 16 + fr) * 32 + quad * 8;
      a_[i] = *(const f16x8*)&sA[r];
    }
#pragma unroll
    for (int j = 0; j < 4; ++j) {
      int r = (j * 16 + fr) * 32 + quad * 8;
      w0[j] = *(const f16x8*)&sW0[r];
      w1[j] = *(const f16x8*)&sW1[r];
      w2[j] = *(const f16x8*)&sW2[r];
    }
#pragma unroll
    for (int i = 0; i < 2; ++i)
#pragma unroll
      for (int j = 0; j < 4; ++j) {
        ar[i][j] = MFMA16(a_[i], w0[j], ar[i][j]);
        az[i][j] = MFMA16(a_[i], w1[j], az[i][j]);
        an_[i][j] = MFMA16(a_[i], w2[j], an_[i][j]);
      }
  }
  // epilogue: full GRU gate update
#pragma unroll
  for (int j = 0; j < 4; ++j) {
    int col = n0 + j * 16 + fr;
    float br = bhh[col], bz = bhh[col + LDIM], bn = bhh[col + 2 * LDIM];
#pragma unroll
    for (int i = 0; i < 2; ++i) {
#pragma unroll
      for (int r = 0; r < 4; ++r) {
        int m = m0 + w * 32 + i * 16 + quad * 4 + r;
        size_t xb = (size_t)m * GDIM + col;
        float xr = (float)xg[xb], xz = (float)xg[xb + LDIM],
              xn = (float)xg[xb + 2 * LDIM];
        size_t si = (size_t)m * LDIM + col;
        float sold = (float)inH[si];
        float rg = sigmoidf_(xr + ar[i][j][r] + br);
        float zg = sigmoidf_(xz + az[i][j][r] + bz);
        float ng = tanhf(xn + rg * (an_[i][j][r] + bn));
        float o = (1.0f - zg) * ng + zg * sold;
        f16 oh = (f16)o;
        outH[si] = oh;
        if (catJH) catJH[(size_t)m * JDIM + col] = oh;
      }
    }
  }
}

// halt = h2[B,1024] @ hw2[2,1024]^T + hb2; one wave per row.
__global__ __launch_bounds__(256) void halt_kernel(
    const float* __restrict__ h2, const float* __restrict__ hw2,
    const float* __restrict__ hb2, float* __restrict__ out) {
  int wave = (blockIdx.x * 256 + threadIdx.x) >> 6;
  int lane = threadIdx.x & 63;
  if (wave >= BATCH) return;
  const float* row = h2 + (size_t)wave * LDIM;
  float s0 = 0.0f, s1 = 0.0f;
#pragma unroll
  for (int k = lane; k < LDIM; k += 64) {
    float v = row[k];
    s0 = fmaf(v, hw2[k], s0);
    s1 = fmaf(v, hw2[LDIM + k], s1);
  }
#pragma unroll
  for (int off = 32; off > 0; off >>= 1) {
    s0 += __shfl_xor(s0, off);
    s1 += __shfl_xor(s1, off);
  }
  if (lane == 0) {
    out[(size_t)wave * 2 + 0] = s0 + hb2[0];
    out[(size_t)wave * 2 + 1] = s1 + hb2[1];
  }
}

extern "C" void kernel_launch(void* const* d_in, const int* in_sizes, int n_in,
                              void* d_out, int out_size, void* d_ws, size_t ws_size,
                              hipStream_t stream) {
  const float* inputs = (const float*)d_in[0];
  const float* W_ih = (const float*)d_in[1];
  const float* W_hh = (const float*)d_in[2];
  const float* b_ih = (const float*)d_in[3];
  const float* b_hh = (const float*)d_in[4];
  const float* aw1 = (const float*)d_in[5];
  const float* ab1 = (const float*)d_in[6];
  const float* aw2 = (const float*)d_in[7];
  const float* ab2 = (const float*)d_in[8];
  const float* hw1 = (const float*)d_in[9];
  const float* hb1 = (const float*)d_in[10];
  const float* hw2 = (const float*)d_in[11];
  const float* hb2 = (const float*)d_in[12];

  float* out = (float*)d_out;
  float* logits_out = out;                               // [8, B, 512]
  float* halt_out = out + (size_t)OUTER * BATCH * ODIM;  // [8, B, 2]

  char* p = (char*)d_ws;
  auto take = [&](size_t bytes) { char* q = p; p += (bytes + 255) & ~255ull; return q; };
  f16* stA = (f16*)take((size_t)BATCH * LDIM * 2);
  f16* stB = (f16*)take((size_t)BATCH * LDIM * 2);
  f16* catX = (f16*)take((size_t)BATCH * JDIM * 2);
  f16* catJ = (f16*)take((size_t)BATCH * JDIM * 2);
  f16* xg = (f16*)take((size_t)BATCH * GDIM * 2);       // 25 MB
  float* h2F = (float*)take((size_t)BATCH * LDIM * 4);
  f16* WihF = (f16*)take((size_t)GDIM * JDIM * 2);
  f16* WhhF = (f16*)take((size_t)GDIM * LDIM * 2);
  f16* WjF = (f16*)take((size_t)(HDIM + LDIM) * JDIM * 2);  // [aw1; hw1]
  f16* aw2F = (f16*)take((size_t)ODIM * HDIM * 2);
  // overlay: h1 fp16 [B,2048] lives in xg region (xg dead after GRU cycles,
  // h1 dead before next step's xg GEMM)
  f16* h1 = xg;

  (void)hipMemsetAsync(stA, 0, (size_t)BATCH * LDIM * 2, stream);
  (void)hipMemsetAsync(catX, 0, (size_t)BATCH * JDIM * 2, stream);
  (void)hipMemsetAsync(catJ, 0, (size_t)BATCH * JDIM * 2, stream);

  auto conv = [&](const float* s, f16* d, size_t n) {
    int n4 = (int)(n / 4);
    convert_w<<<(n4 + 255) / 256, 256, 0, stream>>>(s, d, n4);
  };
  conv(W_ih, WihF, (size_t)GDIM * JDIM);
  conv(W_hh, WhhF, (size_t)GDIM * LDIM);
  conv(aw1, WjF, (size_t)HDIM * JDIM);
  conv(hw1, WjF + (size_t)HDIM * JDIM, (size_t)LDIM * JDIM);
  conv(aw2, aw2F, (size_t)ODIM * HDIM);
  input_to_cat<<<BATCH, 256, 0, stream>>>(inputs, catX);

  for (int s = 0; s < OUTER; ++s) {
    // x_gates = [inputs|ans] @ W_ih^T + b_ih -> fp16 xg
    gemm_f16<0><<<dim3(GDIM / 128, BATCH / 128), 256, 0, stream>>>(
        catX, WihF, b_ih, nullptr, xg, nullptr, nullptr, nullptr, nullptr,
        GDIM, JDIM);
    // 4 fused GRU cycles, ping-pong; last writes catJ state cols
    f16 *cur = stA, *nxt = stB;
    for (int c = 0; c < INNER; ++c) {
      bool last = (c == INNER - 1);
      gru_fused<<<dim3(LDIM / 64, BATCH / 128), 256, 0, stream>>>(
          cur, WhhF, b_hh, xg, nxt, last ? catJ : nullptr);
      f16* t = cur; cur = nxt; nxt = t;
    }
    // h1 = relu(joint @ aw1^T + ab1) fp16 (overlay xg);
    // h2 = relu(joint @ hw1^T + hb1) fp32 — one combined N=3072 GEMM
    gemm_f16<1><<<dim3((HDIM + LDIM) / 128, BATCH / 128), 256, 0, stream>>>(
        catJ, WjF, ab1, hb1, h1, h2F, nullptr, nullptr, nullptr,
        HDIM + LDIM, JDIM);
    // logits = h1 @ aw2^T + ab2 -> out; ans = tanh -> catX/catJ ans cols
    gemm_f16<2><<<dim3(ODIM / 128, BATCH / 128), 256, 0, stream>>>(
        h1, aw2F, ab2, nullptr, nullptr, nullptr,
        logits_out + (size_t)s * BATCH * ODIM, catX, catJ, ODIM, HDIM);
    // halt = h2 @ hw2^T + hb2 -> out
    halt_kernel<<<BATCH / 4, 256, 0, stream>>>(
        h2F, hw2, hb2, halt_out + (size_t)s * BATCH * 2);
  }
}